// Round 5
// baseline (900.041 us; speedup 1.0000x reference)
//
#include <hip/hip_runtime.h>
#include <hip/hip_fp16.h>

#define HD 64
#define SEQ 2304

typedef unsigned short u16;
typedef unsigned int u32;
using f32x4 = __attribute__((ext_vector_type(4))) float;
using s16x8 = __attribute__((ext_vector_type(8))) short;

static __device__ __forceinline__ u16 f2bf(float x) {
  union { float f; u32 u; } a; a.f = x;
  u32 r = a.u + 0x7fffu + ((a.u >> 16) & 1u);
  return (u16)(r >> 16);
}
static __device__ __forceinline__ float bf2f(u16 h) {
  union { float f; u32 u; } a; a.u = ((u32)h) << 16; return a.f;
}

// ---------------- convert + transpose weights: w[K][N] f32 -> wT[N][K] bf16 hi/lo
__global__ __launch_bounds__(256) void conv_wT_k(
    const float* __restrict__ src, u16* __restrict__ dhi, u16* __restrict__ dlo,
    int K, int N)
{
  __shared__ u32 t[64][65];
  const int tid = threadIdx.x;
  const int n0 = blockIdx.x * 64, k0 = blockIdx.y * 64;
  const int r = tid >> 2, c0 = (tid & 3) * 16;
  const float* sp = src + (size_t)(k0 + r) * N + n0 + c0;
#pragma unroll
  for (int j = 0; j < 16; j += 4) {
    f32x4 v = *(const f32x4*)(sp + j);
#pragma unroll
    for (int e = 0; e < 4; e++) {
      float x = v[e];
      u16 h = f2bf(x);
      u16 l = f2bf(x - bf2f(h));
      t[r][c0 + j + e] = (u32)h | ((u32)l << 16);
    }
  }
  __syncthreads();
  u16 hb[16], lb[16];
#pragma unroll
  for (int j = 0; j < 16; j++) {
    u32 p = t[c0 + j][r];
    hb[j] = (u16)(p & 0xffffu);
    lb[j] = (u16)(p >> 16);
  }
  size_t off = (size_t)(n0 + r) * K + k0 + c0;
  *(uint4*)(dhi + off)     = *(uint4*)&hb[0];
  *(uint4*)(dhi + off + 8) = *(uint4*)&hb[8];
  *(uint4*)(dlo + off)     = *(uint4*)&lb[0];
  *(uint4*)(dlo + off + 8) = *(uint4*)&lb[8];
}

// ---------------- QKV GEMM via split-bf16 MFMA: x[4608x768] @ wT -> q fp32 + K/V images
__global__ __launch_bounds__(256) void qkv_mfma_k(
    const float* __restrict__ x, const u16* __restrict__ bthi, const u16* __restrict__ btlo,
    const float* __restrict__ bias,
    float* __restrict__ qbuf, u16* __restrict__ khi, u16* __restrict__ klo,
    u16* __restrict__ vhi, u16* __restrict__ vlo)
{
  __shared__ __align__(16) u16 Ah[128*40], Al[128*40], Bh2[128*40], Bl2[128*40];
  const int tid = threadIdx.x;
  const int lane = tid & 63, wid = tid >> 6;
  const int g = lane >> 4, ql = lane & 15;
  const int wr = wid >> 1, wc = wid & 1;
  const int c0 = blockIdx.x * 128, r0 = blockIdx.y * 128;
  const int srow = tid >> 1, half = tid & 1;

  const float* ag = x + (size_t)(r0 + srow) * 768 + half * 16;
  const u16* bgh = bthi + (size_t)(c0 + srow) * 768 + half * 16;
  const u16* bgl = btlo + (size_t)(c0 + srow) * 768 + half * 16;

  f32x4 pa[4]; uint4 pbh[2], pbl[2];
#pragma unroll
  for (int j = 0; j < 4; j++) pa[j] = *(const f32x4*)(ag + j * 4);
  pbh[0] = *(const uint4*)bgh; pbh[1] = *(const uint4*)(bgh + 8);
  pbl[0] = *(const uint4*)bgl; pbl[1] = *(const uint4*)(bgl + 8);

  f32x4 acc[4][4] = {};

  for (int ks = 0; ks < 24; ks++) {
    __syncthreads();
    {
      u16 hb[16], lb[16];
#pragma unroll
      for (int j = 0; j < 16; j++) {
        float xv = pa[j >> 2][j & 3];
        u16 h = f2bf(xv);
        hb[j] = h; lb[j] = f2bf(xv - bf2f(h));
      }
      u16* d1 = Ah + srow * 40 + half * 16;
      u16* d2 = Al + srow * 40 + half * 16;
      *(uint4*)d1 = *(uint4*)&hb[0];
      *(uint4*)(d1 + 8) = *(uint4*)&hb[8];
      *(uint4*)d2 = *(uint4*)&lb[0];
      *(uint4*)(d2 + 8) = *(uint4*)&lb[8];
      u16* d3 = Bh2 + srow * 40 + half * 16;
      u16* d4 = Bl2 + srow * 40 + half * 16;
      *(uint4*)d3 = pbh[0]; *(uint4*)(d3 + 8) = pbh[1];
      *(uint4*)d4 = pbl[0]; *(uint4*)(d4 + 8) = pbl[1];
    }
    __syncthreads();
    if (ks < 23) {
      const float* a2 = ag + (ks + 1) * 32;
#pragma unroll
      for (int j = 0; j < 4; j++) pa[j] = *(const f32x4*)(a2 + j * 4);
      pbh[0] = *(const uint4*)(bgh + (ks + 1) * 32);
      pbh[1] = *(const uint4*)(bgh + (ks + 1) * 32 + 8);
      pbl[0] = *(const uint4*)(bgl + (ks + 1) * 32);
      pbl[1] = *(const uint4*)(bgl + (ks + 1) * 32 + 8);
    }
    s16x8 bfh[4], bfl[4];
#pragma unroll
    for (int nt = 0; nt < 4; nt++) {
      bfh[nt] = *(const s16x8*)(Bh2 + (wc * 64 + nt * 16 + ql) * 40 + g * 8);
      bfl[nt] = *(const s16x8*)(Bl2 + (wc * 64 + nt * 16 + ql) * 40 + g * 8);
    }
#pragma unroll
    for (int mt = 0; mt < 4; mt++) {
      s16x8 ah = *(const s16x8*)(Ah + (wr * 64 + mt * 16 + ql) * 40 + g * 8);
      s16x8 al = *(const s16x8*)(Al + (wr * 64 + mt * 16 + ql) * 40 + g * 8);
#pragma unroll
      for (int nt = 0; nt < 4; nt++) {
        acc[mt][nt] = __builtin_amdgcn_mfma_f32_16x16x32_bf16(ah, bfh[nt], acc[mt][nt], 0, 0, 0);
        acc[mt][nt] = __builtin_amdgcn_mfma_f32_16x16x32_bf16(ah, bfl[nt], acc[mt][nt], 0, 0, 0);
        acc[mt][nt] = __builtin_amdgcn_mfma_f32_16x16x32_bf16(al, bfh[nt], acc[mt][nt], 0, 0, 0);
      }
    }
  }
  // ---- epilogue: scatter to q fp32 / K,V permuted tile-images
  const int col0 = c0 + wc * 64;
  const int row0 = r0 + wr * 64;
  const int hb36 = col0 >> 6;
  const int which = hb36 / 12, head = hb36 - (hb36 / 12) * 12;
  const int b = row0 / 2304;
  const int sb = row0 - b * 2304;
  const int bh = b * 12 + head;
  float bb[4];
#pragma unroll
  for (int nt = 0; nt < 4; nt++) bb[nt] = bias[col0 + nt * 16 + ql];
  if (which == 0) {
#pragma unroll
    for (int mt = 0; mt < 4; mt++)
#pragma unroll
      for (int nt = 0; nt < 4; nt++)
#pragma unroll
        for (int r = 0; r < 4; r++) {
          int s = sb + mt * 16 + g * 4 + r;
          qbuf[((size_t)bh * SEQ + s) * 64 + nt * 16 + ql] = acc[mt][nt][r] + bb[nt];
        }
  } else {
    const int kt = sb >> 6;
    const size_t tile = ((size_t)bh * 36 + kt) * 4096;
    if (which == 1) {
#pragma unroll
      for (int mt = 0; mt < 4; mt++)
#pragma unroll
        for (int nt = 0; nt < 4; nt++) {
          int pc = (nt >> 1) * 32 + (ql >> 2) * 8 + (nt & 1) * 4 + (ql & 3);
#pragma unroll
          for (int r = 0; r < 4; r++) {
            int key = mt * 16 + g * 4 + r;
            float xv = acc[mt][nt][r] + bb[nt];
            u16 h = f2bf(xv);
            khi[tile + key * 64 + pc] = h;
            klo[tile + key * 64 + pc] = f2bf(xv - bf2f(h));
          }
        }
    } else {
#pragma unroll
      for (int mt = 0; mt < 4; mt++)
#pragma unroll
        for (int nt = 0; nt < 4; nt++)
#pragma unroll
          for (int r = 0; r < 4; r++) {
            int d = nt * 16 + ql;
            int vc = (mt >> 1) * 32 + g * 8 + (mt & 1) * 4 + r;
            float xv = acc[mt][nt][r] + bb[nt];
            u16 h = f2bf(xv);
            vhi[tile + d * 64 + vc] = h;
            vlo[tile + d * 64 + vc] = f2bf(xv - bf2f(h));
          }
    }
  }
}

// ---------------- Fused attention: barrier-free main loop, frags direct global->reg
__global__ __launch_bounds__(512) void attn_k(
    const float* __restrict__ qb,
    const u16* __restrict__ khi, const u16* __restrict__ klo,
    const u16* __restrict__ vhi, const u16* __restrict__ vlo,
    const float* __restrict__ rph, const float* __restrict__ rpw,
    float* __restrict__ ao)
{
  __shared__ __align__(16) char pool[30976];
  float* qlds = (float*)pool;             // prologue [64][68] f32 (17408B)
  float* o_s  = (float*)pool;             // epilogue alias [64][68] f32
  __half* Bh = (__half*)(pool + 17408);   // [48 kh][68 q-pad]  (6528B)
  __half* Bw = (__half*)(pool + 23936);   // [48 kw][68 q-pad]
  float* m_s = (float*)(pool + 30464);    // [64]
  float* l_s = (float*)(pool + 30720);    // [64]

  const int tid  = threadIdx.x;
  const int lane = tid & 63;
  const int wid  = tid >> 6;
  const int g    = lane >> 4;
  const int ql   = lane & 15;
  const int wq   = wid & 3;     // q-group: rows [16*wq, 16*wq+16)
  const int hh   = wid >> 2;    // key-half stream
  const int qt   = blockIdx.x;  // 36
  const int bh   = blockIdx.y;  // 24
  const int s0   = qt * 64;

  // ---- stage Q tile fp32 -> LDS
  {
    int row = tid >> 3, c0 = (tid & 7) * 8;
    const float* src = qb + ((size_t)bh * SEQ + s0 + row) * HD + c0;
    f32x4 v0 = *(const f32x4*)src;
    f32x4 v1 = *(const f32x4*)(src + 4);
    *(f32x4*)&qlds[row * 68 + c0]     = v0;
    *(f32x4*)&qlds[row * 68 + c0 + 4] = v1;
  }
  __syncthreads();

  // ---- Q fragments hi/lo (lane's q = 16*wq + ql)
  s16x8 qfh[2], qfl[2];
  {
    int qrow = wq * 16 + ql;
#pragma unroll
    for (int ds = 0; ds < 2; ds++) {
#pragma unroll
      for (int h2 = 0; h2 < 2; h2++) {
        f32x4 qv = *(const f32x4*)&qlds[qrow * 68 + g * 4 + h2 * 16 + ds * 32];
#pragma unroll
        for (int j = 0; j < 4; j++) {
          float xx = qv[j];
          u16 hi = f2bf(xx);
          u16 lo = f2bf(xx - bf2f(hi));
          qfh[ds][h2 * 4 + j] = (short)hi;
          qfl[ds][h2 * 4 + j] = (short)lo;
        }
      }
    }
  }

  // ---- decomposed rel-pos bias tables (fp16, padded stride 68: conflict-free)
  for (int i = tid; i < 64 * 96; i += 512) {
    int q = i / 96, j = i - (i / 96) * 96;
    int s = s0 + q;
    int qhg = s / 48, qw = s - qhg * 48;
    const float* tab;
    int ridx, col;
    if (j < 48) { col = j;      ridx = qhg - j + 47;        tab = rph; }
    else        { col = j - 48; ridx = qw - (j - 48) + 47;  tab = rpw; }
    const float* rp = tab + (size_t)ridx * HD;
    const float* qp = &qlds[q * 68];
    float s1 = 0.f;
#pragma unroll 4
    for (int d = 0; d < 64; d += 4) {
      f32x4 a = *(const f32x4*)(qp + d);
      f32x4 bv = *(const f32x4*)(rp + d);
      s1 += a[0]*bv[0] + a[1]*bv[1] + a[2]*bv[2] + a[3]*bv[3];
    }
    if (j < 48) Bh[col * 68 + q] = __float2half_rn(s1);
    else        Bw[col * 68 + q] = __float2half_rn(s1);
  }
  __syncthreads();   // bias tables + qlds reads complete; no barriers after this until epilogue

  float m_r = -3.0e38f, l_r = 0.f;
  f32x4 oacc[4] = {};   // O[q = 4g+r][d = ql + 16*dt]
  const int q64b = wq * 16 + ql;
  const size_t tbK = (size_t)bh * 36 * 4096;

  // per-lane fragment offsets within a tile image
  const int koff0 = ((hh * 2 + 0) * 16 + ql) * 64 + g * 8;  // + ds*32
  const int koff1 = ((hh * 2 + 1) * 16 + ql) * 64 + g * 8;
  const int voffb = ql * 64 + hh * 32 + g * 8;              // + dt*16*64

  for (int kt = 0; kt < 36; kt++) {
    const size_t tb = tbK + (size_t)kt * 4096;
    const u16* Kh = khi + tb; const u16* Kl = klo + tb;
    const u16* Vh = vhi + tb; const u16* Vl = vlo + tb;

    // ---- issue all fragment loads (global->reg, L2-resident, no LDS)
    s16x8 af[2][2], al[2][2], bhf[4], blf[4];
#pragma unroll
    for (int ds = 0; ds < 2; ds++) {
      af[ds][0] = *(const s16x8*)(Kh + koff0 + ds * 32);
      af[ds][1] = *(const s16x8*)(Kh + koff1 + ds * 32);
      al[ds][0] = *(const s16x8*)(Kl + koff0 + ds * 32);
      al[ds][1] = *(const s16x8*)(Kl + koff1 + ds * 32);
    }
#pragma unroll
    for (int dt = 0; dt < 4; dt++) {
      bhf[dt] = *(const s16x8*)(Vh + voffb + dt * 1024);
      blf[dt] = *(const s16x8*)(Vl + voffb + dt * 1024);
    }

    // ---- QK^T (swapped): S^T[key][q]
    f32x4 sacc[2] = {};
    __builtin_amdgcn_s_setprio(1);
#pragma unroll
    for (int ds = 0; ds < 2; ds++) {
#pragma unroll
      for (int t2 = 0; t2 < 2; t2++) {
        sacc[t2] = __builtin_amdgcn_mfma_f32_16x16x32_bf16(af[ds][t2], qfh[ds], sacc[t2], 0, 0, 0);
        sacc[t2] = __builtin_amdgcn_mfma_f32_16x16x32_bf16(af[ds][t2], qfl[ds], sacc[t2], 0, 0, 0);
        sacc[t2] = __builtin_amdgcn_mfma_f32_16x16x32_bf16(al[ds][t2], qfh[ds], sacc[t2], 0, 0, 0);
      }
    }
    __builtin_amdgcn_s_setprio(0);

    // ---- bias + online softmax (lane owns q-row q64b; 8 keys in-lane)
    float lg[8];
    float tmax = -3.0e38f;
#pragma unroll
    for (int t2 = 0; t2 < 2; t2++)
#pragma unroll
      for (int r = 0; r < 4; r++) {
        u32 kg = (u32)(kt * 64 + hh * 32 + t2 * 16 + g * 4 + r);
        u32 kh = kg / 48u;
        u32 kw = kg - kh * 48u;
        float x = sacc[t2][r] * 0.125f
                + __half2float(Bh[(int)kh * 68 + q64b])
                + __half2float(Bw[(int)kw * 68 + q64b]);
        lg[t2 * 4 + r] = x;
        tmax = fmaxf(tmax, x);
      }
    tmax = fmaxf(tmax, __shfl_xor(tmax, 16));
    tmax = fmaxf(tmax, __shfl_xor(tmax, 32));
    if (__any(tmax > m_r + 6.0f)) {   // T13 defer-max
      float mnew = fmaxf(m_r, tmax);
      float corr = __expf(m_r - mnew);
      l_r *= corr;
      m_r = mnew;
      float cq[4];
#pragma unroll
      for (int r = 0; r < 4; r++) cq[r] = __shfl(corr, g * 4 + r);
#pragma unroll
      for (int dt = 0; dt < 4; dt++)
#pragma unroll
        for (int r = 0; r < 4; r++) oacc[dt][r] *= cq[r];
    }
    float psum = 0.f;
    s16x8 pfh, pfl;
#pragma unroll
    for (int j = 0; j < 8; j++) {
      float p = __expf(lg[j] - m_r);
      psum += p;
      u16 hi = f2bf(p);
      pfh[j] = (short)hi;
      pfl[j] = (short)f2bf(p - bf2f(hi));
    }
    psum += __shfl_xor(psum, 16);
    psum += __shfl_xor(psum, 32);
    l_r += psum;

    // ---- PV
    __builtin_amdgcn_s_setprio(1);
#pragma unroll
    for (int dt = 0; dt < 4; dt++) {
      oacc[dt] = __builtin_amdgcn_mfma_f32_16x16x32_bf16(pfh, bhf[dt], oacc[dt], 0, 0, 0);
      oacc[dt] = __builtin_amdgcn_mfma_f32_16x16x32_bf16(pfh, blf[dt], oacc[dt], 0, 0, 0);
      oacc[dt] = __builtin_amdgcn_mfma_f32_16x16x32_bf16(pfl, bhf[dt], oacc[dt], 0, 0, 0);
    }
    __builtin_amdgcn_s_setprio(0);
  }

  // ---- merge the two key-streams per q-group, write out
  __syncthreads();
  if (hh == 1) {
    if (g == 0) { m_s[wq * 16 + ql] = m_r; l_s[wq * 16 + ql] = l_r; }
#pragma unroll
    for (int dt = 0; dt < 4; dt++)
#pragma unroll
      for (int r = 0; r < 4; r++)
        o_s[(wq * 16 + g * 4 + r) * 68 + ql + 16 * dt] = oacc[dt][r];
  }
  __syncthreads();
  if (hh == 0) {
    float m2 = m_s[wq * 16 + ql];
    float l2 = l_s[wq * 16 + ql];
    float mf = fmaxf(m_r, m2);
    float c1 = __expf(m_r - mf);
    float c2 = __expf(m2 - mf);
    float lf = l_r * c1 + l2 * c2;
    float c1q[4], c2q[4], lfq[4];
#pragma unroll
    for (int r = 0; r < 4; r++) {
      c1q[r] = __shfl(c1, g * 4 + r);
      c2q[r] = __shfl(c2, g * 4 + r);
      lfq[r] = __shfl(lf, g * 4 + r);
    }
    const int b = bh / 12, head = bh - (bh / 12) * 12;
#pragma unroll
    for (int dt = 0; dt < 4; dt++)
#pragma unroll
      for (int r = 0; r < 4; r++) {
        float oo = oacc[dt][r] * c1q[r]
                 + o_s[(wq * 16 + g * 4 + r) * 68 + ql + 16 * dt] * c2q[r];
        int s = s0 + wq * 16 + g * 4 + r;
        ao[((size_t)b * SEQ + s) * 768 + head * 64 + ql + 16 * dt] = oo / lfq[r];
      }
  }
}

// ---------------- proj GEMM via split-bf16 MFMA: ao[4608x768] @ wpT + bias -> out
__global__ __launch_bounds__(256) void proj_mfma_k(
    const float* __restrict__ a, const u16* __restrict__ bthi, const u16* __restrict__ btlo,
    const float* __restrict__ bias, float* __restrict__ out)
{
  __shared__ __align__(16) u16 Ah[128*40], Al[128*40], Bh2[128*40], Bl2[128*40];
  const int tid = threadIdx.x;
  const int lane = tid & 63, wid = tid >> 6;
  const int g = lane >> 4, ql = lane & 15;
  const int wr = wid >> 1, wc = wid & 1;
  const int c0 = blockIdx.x * 128, r0 = blockIdx.y * 128;
  const int srow = tid >> 1, half = tid & 1;

  const float* ag = a + (size_t)(r0 + srow) * 768 + half * 16;
  const u16* bgh = bthi + (size_t)(c0 + srow) * 768 + half * 16;
  const u16* bgl = btlo + (size_t)(c0 + srow) * 768 + half * 16;

  f32x4 pa[4]; uint4 pbh[2], pbl[2];
#pragma unroll
  for (int j = 0; j < 4; j++) pa[j] = *(const f32x4*)(ag + j * 4);
  pbh[0] = *(const uint4*)bgh; pbh[1] = *(const uint4*)(bgh + 8);
  pbl[0] = *(const uint4*)bgl; pbl[1] = *(const uint4*)(bgl + 8);

  f32x4 acc[4][4] = {};

  for (int ks = 0; ks < 24; ks++) {
    __syncthreads();
    {
      u16 hb[16], lb[16];
#pragma unroll
      for (int j = 0; j < 16; j++) {
        float xv = pa[j >> 2][j & 3];
        u16 h = f2bf(xv);
        hb[j] = h; lb[j] = f2bf(xv - bf2f(h));
      }
      u16* d1 = Ah + srow * 40 + half * 16;
      u16* d2 = Al + srow * 40 + half * 16;
      *(uint4*)d1 = *(uint4*)&hb[0];
      *(uint4*)(d1 + 8) = *(uint4*)&hb[8];
      *(uint4*)d2 = *(uint4*)&lb[0];
      *(uint4*)(d2 + 8) = *(uint4*)&lb[8];
      u16* d3 = Bh2 + srow * 40 + half * 16;
      u16* d4 = Bl2 + srow * 40 + half * 16;
      *(uint4*)d3 = pbh[0]; *(uint4*)(d3 + 8) = pbh[1];
      *(uint4*)d4 = pbl[0]; *(uint4*)(d4 + 8) = pbl[1];
    }
    __syncthreads();
    if (ks < 23) {
      const float* a2 = ag + (ks + 1) * 32;
#pragma unroll
      for (int j = 0; j < 4; j++) pa[j] = *(const f32x4*)(a2 + j * 4);
      pbh[0] = *(const uint4*)(bgh + (ks + 1) * 32);
      pbh[1] = *(const uint4*)(bgh + (ks + 1) * 32 + 8);
      pbl[0] = *(const uint4*)(bgl + (ks + 1) * 32);
      pbl[1] = *(const uint4*)(bgl + (ks + 1) * 32 + 8);
    }
    s16x8 bfh[4], bfl[4];
#pragma unroll
    for (int nt = 0; nt < 4; nt++) {
      bfh[nt] = *(const s16x8*)(Bh2 + (wc * 64 + nt * 16 + ql) * 40 + g * 8);
      bfl[nt] = *(const s16x8*)(Bl2 + (wc * 64 + nt * 16 + ql) * 40 + g * 8);
    }
#pragma unroll
    for (int mt = 0; mt < 4; mt++) {
      s16x8 ah = *(const s16x8*)(Ah + (wr * 64 + mt * 16 + ql) * 40 + g * 8);
      s16x8 al = *(const s16x8*)(Al + (wr * 64 + mt * 16 + ql) * 40 + g * 8);
#pragma unroll
      for (int nt = 0; nt < 4; nt++) {
        acc[mt][nt] = __builtin_amdgcn_mfma_f32_16x16x32_bf16(ah, bfh[nt], acc[mt][nt], 0, 0, 0);
        acc[mt][nt] = __builtin_amdgcn_mfma_f32_16x16x32_bf16(ah, bfl[nt], acc[mt][nt], 0, 0, 0);
        acc[mt][nt] = __builtin_amdgcn_mfma_f32_16x16x32_bf16(al, bfh[nt], acc[mt][nt], 0, 0, 0);
      }
    }
  }
  const int col0 = c0 + wc * 64;
  const int row0 = r0 + wr * 64;
  float bb[4];
#pragma unroll
  for (int nt = 0; nt < 4; nt++) bb[nt] = bias[col0 + nt * 16 + ql];
#pragma unroll
  for (int mt = 0; mt < 4; mt++)
#pragma unroll
    for (int nt = 0; nt < 4; nt++)
#pragma unroll
      for (int r = 0; r < 4; r++)
        out[(size_t)(row0 + mt * 16 + g * 4 + r) * 768 + col0 + nt * 16 + ql] =
            acc[mt][nt][r] + bb[nt];
}

extern "C" void kernel_launch(void* const* d_in, const int* in_sizes, int n_in,
                              void* d_out, int out_size, void* d_ws, size_t ws_size,
                              hipStream_t stream) {
  const float* x      = (const float*)d_in[0];
  const float* qkv_w  = (const float*)d_in[1];
  const float* qkv_b  = (const float*)d_in[2];
  const float* proj_w = (const float*)d_in[3];
  const float* proj_b = (const float*)d_in[4];
  const float* rph    = (const float*)d_in[5];
  const float* rpw    = (const float*)d_in[6];
  float* out = (float*)d_out;
  float* ws  = (float*)d_ws;

  const size_t SZ = (size_t)24 * SEQ * HD;   // 3,538,944 elems
  float* qbuf = ws;                          // SZ f32
  u16* khi = (u16*)(ws + SZ);                // 4 x SZ u16
  u16* klo = khi + SZ;
  u16* vhi = klo + SZ;
  u16* vlo = vhi + SZ;
  float* ao = ws + 3 * SZ;                   // SZ f32
  u16* wqThi = (u16*)(ws + 4 * SZ);          // 768*2304
  u16* wqTlo = wqThi + 768 * 2304;
  u16* wpThi = wqTlo + 768 * 2304;           // 768*768
  u16* wpTlo = wpThi + 768 * 768;

  conv_wT_k <<<dim3(36, 12), 256, 0, stream>>>(qkv_w, wqThi, wqTlo, 768, 2304);
  conv_wT_k <<<dim3(12, 12), 256, 0, stream>>>(proj_w, wpThi, wpTlo, 768, 768);
  qkv_mfma_k<<<dim3(18, 36), 256, 0, stream>>>(x, wqThi, wqTlo, qkv_b,
                                               qbuf, khi, klo, vhi, vlo);
  attn_k    <<<dim3(36, 24), 512, 0, stream>>>(qbuf, khi, klo, vhi, vlo, rph, rpw, ao);
  proj_mfma_k<<<dim3(6, 36), 256, 0, stream>>>(ao, wpThi, wpTlo, proj_b, out);
}

// Round 6
// 555.775 us; speedup vs baseline: 1.6194x; 1.6194x over previous
//
#include <hip/hip_runtime.h>
#include <hip/hip_fp16.h>

#define HD 64
#define SEQ 2304

typedef unsigned short u16;
typedef unsigned int u32;
using f32x4 = __attribute__((ext_vector_type(4))) float;
using s16x8 = __attribute__((ext_vector_type(8))) short;

static __device__ __forceinline__ u16 f2bf(float x) {
  union { float f; u32 u; } a; a.f = x;
  u32 r = a.u + 0x7fffu + ((a.u >> 16) & 1u);
  return (u16)(r >> 16);
}
static __device__ __forceinline__ float bf2f(u16 h) {
  union { float f; u32 u; } a; a.u = ((u32)h) << 16; return a.f;
}

// ---------------- convert + transpose weights: w[K][N] f32 -> wT[N][K] bf16 hi/lo
__global__ __launch_bounds__(256) void conv_wT_k(
    const float* __restrict__ src, u16* __restrict__ dhi, u16* __restrict__ dlo,
    int K, int N)
{
  __shared__ u32 t[64][65];
  const int tid = threadIdx.x;
  const int n0 = blockIdx.x * 64, k0 = blockIdx.y * 64;
  const int r = tid >> 2, c0 = (tid & 3) * 16;
  const float* sp = src + (size_t)(k0 + r) * N + n0 + c0;
#pragma unroll
  for (int j = 0; j < 16; j += 4) {
    f32x4 v = *(const f32x4*)(sp + j);
#pragma unroll
    for (int e = 0; e < 4; e++) {
      float x = v[e];
      u16 h = f2bf(x);
      u16 l = f2bf(x - bf2f(h));
      t[r][c0 + j + e] = (u32)h | ((u32)l << 16);
    }
  }
  __syncthreads();
  u16 hb[16], lb[16];
#pragma unroll
  for (int j = 0; j < 16; j++) {
    u32 p = t[c0 + j][r];
    hb[j] = (u16)(p & 0xffffu);
    lb[j] = (u16)(p >> 16);
  }
  size_t off = (size_t)(n0 + r) * K + k0 + c0;
  *(uint4*)(dhi + off)     = *(uint4*)&hb[0];
  *(uint4*)(dhi + off + 8) = *(uint4*)&hb[8];
  *(uint4*)(dlo + off)     = *(uint4*)&lb[0];
  *(uint4*)(dlo + off + 8) = *(uint4*)&lb[8];
}

// ---------------- QKV GEMM via split-bf16 MFMA: x[4608x768] @ wT -> q fp32 + K/V images
__global__ __launch_bounds__(256) void qkv_mfma_k(
    const float* __restrict__ x, const u16* __restrict__ bthi, const u16* __restrict__ btlo,
    const float* __restrict__ bias,
    float* __restrict__ qbuf, u16* __restrict__ khi, u16* __restrict__ klo,
    u16* __restrict__ vhi, u16* __restrict__ vlo)
{
  __shared__ __align__(16) u16 Ah[128*40], Al[128*40], Bh2[128*40], Bl2[128*40];
  const int tid = threadIdx.x;
  const int lane = tid & 63, wid = tid >> 6;
  const int g = lane >> 4, ql = lane & 15;
  const int wr = wid >> 1, wc = wid & 1;
  const int c0 = blockIdx.x * 128, r0 = blockIdx.y * 128;
  const int srow = tid >> 1, half = tid & 1;

  const float* ag = x + (size_t)(r0 + srow) * 768 + half * 16;
  const u16* bgh = bthi + (size_t)(c0 + srow) * 768 + half * 16;
  const u16* bgl = btlo + (size_t)(c0 + srow) * 768 + half * 16;

  f32x4 pa[4]; uint4 pbh[2], pbl[2];
#pragma unroll
  for (int j = 0; j < 4; j++) pa[j] = *(const f32x4*)(ag + j * 4);
  pbh[0] = *(const uint4*)bgh; pbh[1] = *(const uint4*)(bgh + 8);
  pbl[0] = *(const uint4*)bgl; pbl[1] = *(const uint4*)(bgl + 8);

  f32x4 acc[4][4] = {};

  for (int ks = 0; ks < 24; ks++) {
    __syncthreads();
    {
      u16 hb[16], lb[16];
#pragma unroll
      for (int j = 0; j < 16; j++) {
        float xv = pa[j >> 2][j & 3];
        u16 h = f2bf(xv);
        hb[j] = h; lb[j] = f2bf(xv - bf2f(h));
      }
      u16* d1 = Ah + srow * 40 + half * 16;
      u16* d2 = Al + srow * 40 + half * 16;
      *(uint4*)d1 = *(uint4*)&hb[0];
      *(uint4*)(d1 + 8) = *(uint4*)&hb[8];
      *(uint4*)d2 = *(uint4*)&lb[0];
      *(uint4*)(d2 + 8) = *(uint4*)&lb[8];
      u16* d3 = Bh2 + srow * 40 + half * 16;
      u16* d4 = Bl2 + srow * 40 + half * 16;
      *(uint4*)d3 = pbh[0]; *(uint4*)(d3 + 8) = pbh[1];
      *(uint4*)d4 = pbl[0]; *(uint4*)(d4 + 8) = pbl[1];
    }
    __syncthreads();
    if (ks < 23) {
      const float* a2 = ag + (ks + 1) * 32;
#pragma unroll
      for (int j = 0; j < 4; j++) pa[j] = *(const f32x4*)(a2 + j * 4);
      pbh[0] = *(const uint4*)(bgh + (ks + 1) * 32);
      pbh[1] = *(const uint4*)(bgh + (ks + 1) * 32 + 8);
      pbl[0] = *(const uint4*)(bgl + (ks + 1) * 32);
      pbl[1] = *(const uint4*)(bgl + (ks + 1) * 32 + 8);
    }
    s16x8 bfh[4], bfl[4];
#pragma unroll
    for (int nt = 0; nt < 4; nt++) {
      bfh[nt] = *(const s16x8*)(Bh2 + (wc * 64 + nt * 16 + ql) * 40 + g * 8);
      bfl[nt] = *(const s16x8*)(Bl2 + (wc * 64 + nt * 16 + ql) * 40 + g * 8);
    }
#pragma unroll
    for (int mt = 0; mt < 4; mt++) {
      s16x8 ah = *(const s16x8*)(Ah + (wr * 64 + mt * 16 + ql) * 40 + g * 8);
      s16x8 al = *(const s16x8*)(Al + (wr * 64 + mt * 16 + ql) * 40 + g * 8);
#pragma unroll
      for (int nt = 0; nt < 4; nt++) {
        acc[mt][nt] = __builtin_amdgcn_mfma_f32_16x16x32_bf16(ah, bfh[nt], acc[mt][nt], 0, 0, 0);
        acc[mt][nt] = __builtin_amdgcn_mfma_f32_16x16x32_bf16(ah, bfl[nt], acc[mt][nt], 0, 0, 0);
        acc[mt][nt] = __builtin_amdgcn_mfma_f32_16x16x32_bf16(al, bfh[nt], acc[mt][nt], 0, 0, 0);
      }
    }
  }
  // ---- epilogue: scatter to q fp32 / K,V permuted tile-images
  const int col0 = c0 + wc * 64;
  const int row0 = r0 + wr * 64;
  const int hb36 = col0 >> 6;
  const int which = hb36 / 12, head = hb36 - (hb36 / 12) * 12;
  const int b = row0 / 2304;
  const int sb = row0 - b * 2304;
  const int bh = b * 12 + head;
  float bb[4];
#pragma unroll
  for (int nt = 0; nt < 4; nt++) bb[nt] = bias[col0 + nt * 16 + ql];
  if (which == 0) {
#pragma unroll
    for (int mt = 0; mt < 4; mt++)
#pragma unroll
      for (int nt = 0; nt < 4; nt++)
#pragma unroll
        for (int r = 0; r < 4; r++) {
          int s = sb + mt * 16 + g * 4 + r;
          qbuf[((size_t)bh * SEQ + s) * 64 + nt * 16 + ql] = acc[mt][nt][r] + bb[nt];
        }
  } else {
    const int kt = sb >> 6;
    const size_t tile = ((size_t)bh * 36 + kt) * 4096;
    if (which == 1) {
#pragma unroll
      for (int mt = 0; mt < 4; mt++)
#pragma unroll
        for (int nt = 0; nt < 4; nt++) {
          int pc = (nt >> 1) * 32 + (ql >> 2) * 8 + (nt & 1) * 4 + (ql & 3);
#pragma unroll
          for (int r = 0; r < 4; r++) {
            int key = mt * 16 + g * 4 + r;
            float xv = acc[mt][nt][r] + bb[nt];
            u16 h = f2bf(xv);
            khi[tile + key * 64 + pc] = h;
            klo[tile + key * 64 + pc] = f2bf(xv - bf2f(h));
          }
        }
    } else {
#pragma unroll
      for (int mt = 0; mt < 4; mt++)
#pragma unroll
        for (int nt = 0; nt < 4; nt++)
#pragma unroll
          for (int r = 0; r < 4; r++) {
            int d = nt * 16 + ql;
            int vc = (mt >> 1) * 32 + g * 8 + (mt & 1) * 4 + r;
            float xv = acc[mt][nt][r] + bb[nt];
            u16 h = f2bf(xv);
            vhi[tile + d * 64 + vc] = h;
            vlo[tile + d * 64 + vc] = f2bf(xv - bf2f(h));
          }
    }
  }
}

// ---------------- Fused attention: LDS-staged K/V tiles, 128 q-rows/block (2x reuse),
// split-bf16 MFMA, swapped QK^T, online softmax. grid(bh=24, qt=18): bh%8 pins to XCD L2.
__global__ __launch_bounds__(512, 4) void attn_k(
    const float* __restrict__ qb,
    const u16* __restrict__ khi, const u16* __restrict__ klo,
    const u16* __restrict__ vhi, const u16* __restrict__ vlo,
    const float* __restrict__ rph, const float* __restrict__ rpw,
    float* __restrict__ ao)
{
  __shared__ __align__(16) char pool[63232];
  u16* KhiL = (u16*)pool;              // [64 key][72]
  u16* KloL = (u16*)(pool + 9216);
  u16* VhL  = (u16*)(pool + 18432);    // [64 d][72]
  u16* VlL  = (u16*)(pool + 27648);
  __half* Bh = (__half*)(pool + 36864);   // [48 kh][132 q-pad]
  __half* Bw = (__half*)(pool + 49536);   // [48 kw][132 q-pad]
  float* m_s = (float*)(pool + 62208);    // [128]
  float* l_s = (float*)(pool + 62720);    // [128]
  float* qlds = (float*)pool;             // prologue alias [128][68] f32 (34816B)
  float* o_s  = (float*)pool;             // epilogue alias [128][68] f32

  const int tid  = threadIdx.x;
  const int lane = tid & 63;
  const int wid  = tid >> 6;
  const int g    = lane >> 4;
  const int ql   = lane & 15;
  const int wqq  = wid & 3;     // q-quad: rows [32*wqq, 32*wqq+32)
  const int hh   = wid >> 2;    // key-half stream
  const int bh   = blockIdx.x;  // 24 (x-major dispatch: XCD = bh % 8)
  const int qt   = blockIdx.y;  // 18
  const int s0   = qt * 128;

  // ---- stage Q tile fp32 -> LDS (128 rows)
  {
    int row = tid >> 2, c0 = (tid & 3) * 16;
    const float* src = qb + ((size_t)bh * SEQ + s0 + row) * HD + c0;
#pragma unroll
    for (int j = 0; j < 16; j += 4)
      *(f32x4*)&qlds[row * 68 + c0 + j] = *(const f32x4*)(src + j);
  }
  __syncthreads();

  // ---- Q fragments hi/lo: [qsub][ds]; lane's q-rows = wqq*32 + qsub*16 + ql
  s16x8 qfh[2][2], qfl[2][2];
#pragma unroll
  for (int qs = 0; qs < 2; qs++) {
    int qrow = wqq * 32 + qs * 16 + ql;
#pragma unroll
    for (int ds = 0; ds < 2; ds++) {
#pragma unroll
      for (int h2 = 0; h2 < 2; h2++) {
        f32x4 qv = *(const f32x4*)&qlds[qrow * 68 + g * 4 + h2 * 16 + ds * 32];
#pragma unroll
        for (int j = 0; j < 4; j++) {
          float xx = qv[j];
          u16 hi = f2bf(xx);
          u16 lo = f2bf(xx - bf2f(hi));
          qfh[qs][ds][h2 * 4 + j] = (short)hi;
          qfl[qs][ds][h2 * 4 + j] = (short)lo;
        }
      }
    }
  }

  // ---- prefetch tile 0; chunk-permuted staging (conflict-free writes)
  const size_t tbK = (size_t)bh * 36 * 4096;
  const int srow = tid >> 3;
  const int sch  = ((tid & 7) - (srow & 7)) & 7;
  const size_t soff = (size_t)srow * 64 + sch * 8;
  uint4 rkh = *(const uint4*)(khi + tbK + soff);
  uint4 rkl = *(const uint4*)(klo + tbK + soff);
  uint4 rvh = *(const uint4*)(vhi + tbK + soff);
  uint4 rvl = *(const uint4*)(vlo + tbK + soff);

  // ---- decomposed rel-pos bias tables (fp16, padded stride 132)
  for (int i = tid; i < 128 * 96; i += 512) {
    int q = i / 96, j = i - (i / 96) * 96;
    int s = s0 + q;
    int qhg = s / 48, qw = s - qhg * 48;
    const float* tab;
    int ridx, col;
    if (j < 48) { col = j;      ridx = qhg - j + 47;        tab = rph; }
    else        { col = j - 48; ridx = qw - (j - 48) + 47;  tab = rpw; }
    const float* rp = tab + (size_t)ridx * HD;
    const float* qp = &qlds[q * 68];
    float s1 = 0.f;
#pragma unroll 4
    for (int d = 0; d < 64; d += 4) {
      f32x4 a = *(const f32x4*)(qp + d);
      f32x4 bv = *(const f32x4*)(rp + d);
      s1 += a[0]*bv[0] + a[1]*bv[1] + a[2]*bv[2] + a[3]*bv[3];
    }
    if (j < 48) Bh[col * 132 + q] = __float2half_rn(s1);
    else        Bw[col * 132 + q] = __float2half_rn(s1);
  }

  float m_r[2] = {-3.0e38f, -3.0e38f};
  float l_r[2] = {0.f, 0.f};
  f32x4 oacc[2][4] = {};   // [qsub][dt]: O[q = qsub-tile + 4g+r][d = ql + 16*dt]

  for (int kt = 0; kt < 36; kt++) {
    __syncthreads();   // prev tile's frag reads done (first iter: bias/qlds reads done)
    *(uint4*)(KhiL + srow * 72 + sch * 8) = rkh;
    *(uint4*)(KloL + srow * 72 + sch * 8) = rkl;
    *(uint4*)(VhL  + srow * 72 + sch * 8) = rvh;
    *(uint4*)(VlL  + srow * 72 + sch * 8) = rvl;
    __syncthreads();
    if (kt < 35) {     // T14: issue next-tile loads; land under MFMA phase
      size_t tb = tbK + (size_t)(kt + 1) * 4096;
      rkh = *(const uint4*)(khi + tb + soff);
      rkl = *(const uint4*)(klo + tb + soff);
      rvh = *(const uint4*)(vhi + tb + soff);
      rvl = *(const uint4*)(vlo + tb + soff);
    }

    // ---- QK^T (swapped): S^T[key][q] for both q-subtiles
    f32x4 sacc[2][2] = {};   // [t2][qsub]
    __builtin_amdgcn_s_setprio(1);
#pragma unroll
    for (int ds = 0; ds < 2; ds++) {
#pragma unroll
      for (int t2 = 0; t2 < 2; t2++) {
        int row = (hh * 2 + t2) * 16 + ql;
        s16x8 af = *(const s16x8*)(KhiL + row * 72 + ds * 32 + g * 8);
        s16x8 al = *(const s16x8*)(KloL + row * 72 + ds * 32 + g * 8);
#pragma unroll
        for (int qs = 0; qs < 2; qs++) {
          sacc[t2][qs] = __builtin_amdgcn_mfma_f32_16x16x32_bf16(af, qfh[qs][ds], sacc[t2][qs], 0, 0, 0);
          sacc[t2][qs] = __builtin_amdgcn_mfma_f32_16x16x32_bf16(af, qfl[qs][ds], sacc[t2][qs], 0, 0, 0);
          sacc[t2][qs] = __builtin_amdgcn_mfma_f32_16x16x32_bf16(al, qfh[qs][ds], sacc[t2][qs], 0, 0, 0);
        }
      }
    }
    __builtin_amdgcn_s_setprio(0);

    // ---- bias + online softmax per q-subtile (lane owns q-row; 8 keys in-lane)
    s16x8 pfh[2], pfl[2];
#pragma unroll
    for (int qs = 0; qs < 2; qs++) {
      const int q128 = wqq * 32 + qs * 16 + ql;
      float lg[8];
      float tmax = -3.0e38f;
#pragma unroll
      for (int t2 = 0; t2 < 2; t2++)
#pragma unroll
        for (int r = 0; r < 4; r++) {
          u32 kg = (u32)(kt * 64 + hh * 32 + t2 * 16 + g * 4 + r);
          u32 kh = kg / 48u;
          u32 kw = kg - kh * 48u;
          float x = sacc[t2][qs][r] * 0.125f
                  + __half2float(Bh[(int)kh * 132 + q128])
                  + __half2float(Bw[(int)kw * 132 + q128]);
          lg[t2 * 4 + r] = x;
          tmax = fmaxf(tmax, x);
        }
      tmax = fmaxf(tmax, __shfl_xor(tmax, 16));
      tmax = fmaxf(tmax, __shfl_xor(tmax, 32));
      if (__any(tmax > m_r[qs] + 6.0f)) {   // T13 defer-max
        float mnew = fmaxf(m_r[qs], tmax);
        float corr = __expf(m_r[qs] - mnew);
        l_r[qs] *= corr;
        m_r[qs] = mnew;
        float cq[4];
#pragma unroll
        for (int r = 0; r < 4; r++) cq[r] = __shfl(corr, g * 4 + r);
#pragma unroll
        for (int dt = 0; dt < 4; dt++)
#pragma unroll
          for (int r = 0; r < 4; r++) oacc[qs][dt][r] *= cq[r];
      }
      float psum = 0.f;
#pragma unroll
      for (int j = 0; j < 8; j++) {
        float p = __expf(lg[j] - m_r[qs]);
        psum += p;
        u16 hi = f2bf(p);
        pfh[qs][j] = (short)hi;
        pfl[qs][j] = (short)f2bf(p - bf2f(hi));
      }
      psum += __shfl_xor(psum, 16);
      psum += __shfl_xor(psum, 32);
      l_r[qs] += psum;
    }

    // ---- PV: each V-frag read feeds both q-subtiles
    __builtin_amdgcn_s_setprio(1);
#pragma unroll
    for (int dt = 0; dt < 4; dt++) {
      int row = ql + 16 * dt;
      s16x8 bhf = *(const s16x8*)(VhL + row * 72 + hh * 32 + g * 8);
      s16x8 blf = *(const s16x8*)(VlL + row * 72 + hh * 32 + g * 8);
#pragma unroll
      for (int qs = 0; qs < 2; qs++) {
        oacc[qs][dt] = __builtin_amdgcn_mfma_f32_16x16x32_bf16(pfh[qs], bhf, oacc[qs][dt], 0, 0, 0);
        oacc[qs][dt] = __builtin_amdgcn_mfma_f32_16x16x32_bf16(pfh[qs], blf, oacc[qs][dt], 0, 0, 0);
        oacc[qs][dt] = __builtin_amdgcn_mfma_f32_16x16x32_bf16(pfl[qs], bhf, oacc[qs][dt], 0, 0, 0);
      }
    }
    __builtin_amdgcn_s_setprio(0);
  }

  // ---- merge the two key-streams per q-row, write out
  __syncthreads();
  if (hh == 1) {
#pragma unroll
    for (int qs = 0; qs < 2; qs++) {
      if (g == 0) {
        m_s[wqq * 32 + qs * 16 + ql] = m_r[qs];
        l_s[wqq * 32 + qs * 16 + ql] = l_r[qs];
      }
#pragma unroll
      for (int dt = 0; dt < 4; dt++)
#pragma unroll
        for (int r = 0; r < 4; r++)
          o_s[(wqq * 32 + qs * 16 + g * 4 + r) * 68 + ql + 16 * dt] = oacc[qs][dt][r];
    }
  }
  __syncthreads();
  if (hh == 0) {
    const int b = bh / 12, head = bh - (bh / 12) * 12;
#pragma unroll
    for (int qs = 0; qs < 2; qs++) {
      const int q128 = wqq * 32 + qs * 16 + ql;
      float m2 = m_s[q128];
      float l2 = l_s[q128];
      float mf = fmaxf(m_r[qs], m2);
      float c1 = __expf(m_r[qs] - mf);
      float c2 = __expf(m2 - mf);
      float lf = l_r[qs] * c1 + l2 * c2;
      float c1q[4], c2q[4], lfq[4];
#pragma unroll
      for (int r = 0; r < 4; r++) {
        c1q[r] = __shfl(c1, g * 4 + r);
        c2q[r] = __shfl(c2, g * 4 + r);
        lfq[r] = __shfl(lf, g * 4 + r);
      }
#pragma unroll
      for (int dt = 0; dt < 4; dt++)
#pragma unroll
        for (int r = 0; r < 4; r++) {
          float oo = oacc[qs][dt][r] * c1q[r]
                   + o_s[(wqq * 32 + qs * 16 + g * 4 + r) * 68 + ql + 16 * dt] * c2q[r];
          int s = s0 + wqq * 32 + qs * 16 + g * 4 + r;
          ao[((size_t)b * SEQ + s) * 768 + head * 64 + ql + 16 * dt] = oo / lfq[r];
        }
    }
  }
}

// ---------------- proj GEMM via split-bf16 MFMA: ao[4608x768] @ wpT + bias -> out
__global__ __launch_bounds__(256) void proj_mfma_k(
    const float* __restrict__ a, const u16* __restrict__ bthi, const u16* __restrict__ btlo,
    const float* __restrict__ bias, float* __restrict__ out)
{
  __shared__ __align__(16) u16 Ah[128*40], Al[128*40], Bh2[128*40], Bl2[128*40];
  const int tid = threadIdx.x;
  const int lane = tid & 63, wid = tid >> 6;
  const int g = lane >> 4, ql = lane & 15;
  const int wr = wid >> 1, wc = wid & 1;
  const int c0 = blockIdx.x * 128, r0 = blockIdx.y * 128;
  const int srow = tid >> 1, half = tid & 1;

  const float* ag = a + (size_t)(r0 + srow) * 768 + half * 16;
  const u16* bgh = bthi + (size_t)(c0 + srow) * 768 + half * 16;
  const u16* bgl = btlo + (size_t)(c0 + srow) * 768 + half * 16;

  f32x4 pa[4]; uint4 pbh[2], pbl[2];
#pragma unroll
  for (int j = 0; j < 4; j++) pa[j] = *(const f32x4*)(ag + j * 4);
  pbh[0] = *(const uint4*)bgh; pbh[1] = *(const uint4*)(bgh + 8);
  pbl[0] = *(const uint4*)bgl; pbl[1] = *(const uint4*)(bgl + 8);

  f32x4 acc[4][4] = {};

  for (int ks = 0; ks < 24; ks++) {
    __syncthreads();
    {
      u16 hb[16], lb[16];
#pragma unroll
      for (int j = 0; j < 16; j++) {
        float xv = pa[j >> 2][j & 3];
        u16 h = f2bf(xv);
        hb[j] = h; lb[j] = f2bf(xv - bf2f(h));
      }
      u16* d1 = Ah + srow * 40 + half * 16;
      u16* d2 = Al + srow * 40 + half * 16;
      *(uint4*)d1 = *(uint4*)&hb[0];
      *(uint4*)(d1 + 8) = *(uint4*)&hb[8];
      *(uint4*)d2 = *(uint4*)&lb[0];
      *(uint4*)(d2 + 8) = *(uint4*)&lb[8];
      u16* d3 = Bh2 + srow * 40 + half * 16;
      u16* d4 = Bl2 + srow * 40 + half * 16;
      *(uint4*)d3 = pbh[0]; *(uint4*)(d3 + 8) = pbh[1];
      *(uint4*)d4 = pbl[0]; *(uint4*)(d4 + 8) = pbl[1];
    }
    __syncthreads();
    if (ks < 23) {
      const float* a2 = ag + (ks + 1) * 32;
#pragma unroll
      for (int j = 0; j < 4; j++) pa[j] = *(const f32x4*)(a2 + j * 4);
      pbh[0] = *(const uint4*)(bgh + (ks + 1) * 32);
      pbh[1] = *(const uint4*)(bgh + (ks + 1) * 32 + 8);
      pbl[0] = *(const uint4*)(bgl + (ks + 1) * 32);
      pbl[1] = *(const uint4*)(bgl + (ks + 1) * 32 + 8);
    }
    s16x8 bfh[4], bfl[4];
#pragma unroll
    for (int nt = 0; nt < 4; nt++) {
      bfh[nt] = *(const s16x8*)(Bh2 + (wc * 64 + nt * 16 + ql) * 40 + g * 8);
      bfl[nt] = *(const s16x8*)(Bl2 + (wc * 64 + nt * 16 + ql) * 40 + g * 8);
    }
#pragma unroll
    for (int mt = 0; mt < 4; mt++) {
      s16x8 ah = *(const s16x8*)(Ah + (wr * 64 + mt * 16 + ql) * 40 + g * 8);
      s16x8 al = *(const s16x8*)(Al + (wr * 64 + mt * 16 + ql) * 40 + g * 8);
#pragma unroll
      for (int nt = 0; nt < 4; nt++) {
        acc[mt][nt] = __builtin_amdgcn_mfma_f32_16x16x32_bf16(ah, bfh[nt], acc[mt][nt], 0, 0, 0);
        acc[mt][nt] = __builtin_amdgcn_mfma_f32_16x16x32_bf16(ah, bfl[nt], acc[mt][nt], 0, 0, 0);
        acc[mt][nt] = __builtin_amdgcn_mfma_f32_16x16x32_bf16(al, bfh[nt], acc[mt][nt], 0, 0, 0);
      }
    }
  }
  const int col0 = c0 + wc * 64;
  const int row0 = r0 + wr * 64;
  float bb[4];
#pragma unroll
  for (int nt = 0; nt < 4; nt++) bb[nt] = bias[col0 + nt * 16 + ql];
#pragma unroll
  for (int mt = 0; mt < 4; mt++)
#pragma unroll
    for (int nt = 0; nt < 4; nt++)
#pragma unroll
      for (int r = 0; r < 4; r++)
        out[(size_t)(row0 + mt * 16 + g * 4 + r) * 768 + col0 + nt * 16 + ql] =
            acc[mt][nt][r] + bb[nt];
}

extern "C" void kernel_launch(void* const* d_in, const int* in_sizes, int n_in,
                              void* d_out, int out_size, void* d_ws, size_t ws_size,
                              hipStream_t stream) {
  const float* x      = (const float*)d_in[0];
  const float* qkv_w  = (const float*)d_in[1];
  const float* qkv_b  = (const float*)d_in[2];
  const float* proj_w = (const float*)d_in[3];
  const float* proj_b = (const float*)d_in[4];
  const float* rph    = (const float*)d_in[5];
  const float* rpw    = (const float*)d_in[6];
  float* out = (float*)d_out;
  float* ws  = (float*)d_ws;

  const size_t SZ = (size_t)24 * SEQ * HD;   // 3,538,944 elems
  float* qbuf = ws;                          // SZ f32
  u16* khi = (u16*)(ws + SZ);                // 4 x SZ u16
  u16* klo = khi + SZ;
  u16* vhi = klo + SZ;
  u16* vlo = vhi + SZ;
  float* ao = ws + 3 * SZ;                   // SZ f32
  u16* wqThi = (u16*)(ws + 4 * SZ);          // 768*2304
  u16* wqTlo = wqThi + 768 * 2304;
  u16* wpThi = wqTlo + 768 * 2304;           // 768*768
  u16* wpTlo = wpThi + 768 * 768;

  conv_wT_k <<<dim3(36, 12), 256, 0, stream>>>(qkv_w, wqThi, wqTlo, 768, 2304);
  conv_wT_k <<<dim3(12, 12), 256, 0, stream>>>(proj_w, wpThi, wpTlo, 768, 768);
  qkv_mfma_k<<<dim3(18, 36), 256, 0, stream>>>(x, wqThi, wqTlo, qkv_b,
                                               qbuf, khi, klo, vhi, vlo);
  attn_k    <<<dim3(24, 18), 512, 0, stream>>>(qbuf, khi, klo, vhi, vlo, rph, rpw, ao);
  proj_mfma_k<<<dim3(6, 36), 256, 0, stream>>>(ao, wpThi, wpTlo, proj_b, out);
}